// Round 10
// baseline (5616.713 us; speedup 1.0000x reference)
//
#include <hip/hip_runtime.h>
#include <stdint.h>

#define S_LEN 2048
#define B_SZ  64
#define I_SZ  512
#define H_SZ  512

typedef __attribute__((ext_vector_type(8))) short bf16x8;
typedef __attribute__((ext_vector_type(4))) float f32x4;

__device__ __forceinline__ uint16_t f2b(float x) {
    uint32_t u = __float_as_uint(x);
    uint32_t r = (u + 0x7fffu + ((u >> 16) & 1u)) >> 16;
    return (uint16_t)r;
}

__device__ __forceinline__ float tfun(float v) {
    float e = __expf(2.f * v);
    return 1.f - 2.f / (e + 1.f);
}

// ---------------- kernel 1: convert W_hh to bf16 in ws ----------------
__global__ void cvt_weights_kernel(const float* __restrict__ whh,
                                   uint16_t* __restrict__ whhb) {
    int i = (blockIdx.x * blockDim.x + threadIdx.x) * 4;
    float4 b = *reinterpret_cast<const float4*>(whh + i);
    union { uint16_t u[4]; uint2 v; } pb;
    pb.u[0] = f2b(b.x); pb.u[1] = f2b(b.y); pb.u[2] = f2b(b.z); pb.u[3] = f2b(b.w);
    *reinterpret_cast<uint2*>(whhb + i) = pb.v;
}

// ---------------- kernel 2: x_proj GEMM (f32 in, cvt on the fly) ----
#define BM 128
#define BN 128
#define BK 32

__launch_bounds__(256)
__global__ void xproj_gemm_kernel(const float* __restrict__ inp,      // [SB, I] f32
                                  const float* __restrict__ wih,      // [H, I] f32
                                  const float* __restrict__ bih,
                                  const float* __restrict__ bhh,
                                  float* __restrict__ xp)             // [SB, H] f32 (= d_out)
{
    __shared__ __align__(16) uint16_t Asm[2][BM * BK];
    __shared__ __align__(16) uint16_t Bsm[2][BN * BK];

    const int tid  = threadIdx.x;
    const int lane = tid & 63;
    const int w    = tid >> 6;
    const int wm   = (w >> 1) * 64;
    const int wn   = (w & 1) * 64;
    const int bid  = blockIdx.x;
    const int m0   = (bid >> 2) * BM;
    const int n0   = (bid & 3) * BN;

    const int srow  = tid >> 1;
    const int shalf = (tid & 1) * 16;

    float bsum[4];
#pragma unroll
    for (int nn = 0; nn < 4; ++nn) {
        int col = n0 + wn + nn * 16 + (lane & 15);
        bsum[nn] = bih[col] + bhh[col];
    }

    f32x4 acc[4][4];
#pragma unroll
    for (int mm = 0; mm < 4; ++mm)
#pragma unroll
        for (int nn = 0; nn < 4; ++nn)
            acc[mm][nn] = f32x4{0.f, 0.f, 0.f, 0.f};

    float4 ar[4], br[4];

    auto loadA = [&](int kt) {
        const float* g = inp + (size_t)(m0 + srow) * I_SZ + kt * BK + shalf;
#pragma unroll
        for (int q = 0; q < 4; ++q) ar[q] = *reinterpret_cast<const float4*>(g + q * 4);
    };
    auto loadB = [&](int kt) {
        const float* g = wih + (size_t)(n0 + srow) * I_SZ + kt * BK + shalf;
#pragma unroll
        for (int q = 0; q < 4; ++q) br[q] = *reinterpret_cast<const float4*>(g + q * 4);
    };
    auto cvt16 = [&](float4* src, uint16_t* dst) {
        alignas(16) uint16_t tmp[16];
#pragma unroll
        for (int q = 0; q < 4; ++q) {
            tmp[q * 4 + 0] = f2b(src[q].x); tmp[q * 4 + 1] = f2b(src[q].y);
            tmp[q * 4 + 2] = f2b(src[q].z); tmp[q * 4 + 3] = f2b(src[q].w);
        }
        *reinterpret_cast<bf16x8*>(dst)     = *reinterpret_cast<bf16x8*>(tmp);
        *reinterpret_cast<bf16x8*>(dst + 8) = *reinterpret_cast<bf16x8*>(tmp + 8);
    };
    auto writeA = [&](int buf) { cvt16(ar, &Asm[buf][srow * BK + shalf]); };
    auto writeB = [&](int buf) { cvt16(br, &Bsm[buf][srow * BK + shalf]); };

    loadA(0); loadB(0); writeA(0); writeB(0);
    __syncthreads();

    for (int kt = 0; kt < I_SZ / BK; ++kt) {
        const int cur = kt & 1;
        const bool more = (kt + 1) < I_SZ / BK;
        if (more) { loadA(kt + 1); loadB(kt + 1); }

        bf16x8 afrag[4], bfrag[4];
#pragma unroll
        for (int mm = 0; mm < 4; ++mm)
            afrag[mm] = *reinterpret_cast<const bf16x8*>(
                &Asm[cur][(wm + mm * 16 + (lane & 15)) * BK + (lane >> 4) * 8]);
#pragma unroll
        for (int nn = 0; nn < 4; ++nn)
            bfrag[nn] = *reinterpret_cast<const bf16x8*>(
                &Bsm[cur][(wn + nn * 16 + (lane & 15)) * BK + (lane >> 4) * 8]);
#pragma unroll
        for (int mm = 0; mm < 4; ++mm)
#pragma unroll
            for (int nn = 0; nn < 4; ++nn)
                acc[mm][nn] = __builtin_amdgcn_mfma_f32_16x16x32_bf16(
                    afrag[mm], bfrag[nn], acc[mm][nn], 0, 0, 0);

        if (more) { writeA(cur ^ 1); writeB(cur ^ 1); }
        __syncthreads();
    }

#pragma unroll
    for (int mm = 0; mm < 4; ++mm) {
        const int rbase = m0 + wm + mm * 16 + (lane >> 4) * 4;
#pragma unroll
        for (int nn = 0; nn < 4; ++nn) {
            const int col = n0 + wn + nn * 16 + (lane & 15);
#pragma unroll
            for (int r = 0; r < 4; ++r)
                xp[(size_t)(rbase + r) * H_SZ + col] = acc[mm][nn][r] + bsum[nn];
        }
    }
}

// ---------------- kernel 3: recurrence ----------------
// Three-pipe balance (model: step ~= instr-throughput of the busiest pipe):
//   - W jt0..2 (48 frags): 192 AGPRs, empty-asm pin + BUILTIN mfma (compiler
//     owns hazards and scheduling; R7/R9's asm-MFMA blocked load hoisting and
//     cost +1800 cyc/step). Pins only hold if arch VGPRs <= 64 -> lean epilogue.
//   - W jt3: 4 frags from LDS (WD, 32 KB) + 12 frags from GLOBAL L2 (constant
//     per-lane addresses: 1 voffset + imm offsets; ~96 KB/step/CU ~ 1536 cyc)
//   - h: LDS hsm double-buffer, 16 broadcast reads/lane (structural minimum)
//   - LDS pipe: (16 h + 4 W) x 8 waves x 12 cyc ~ 1920 cyc/step; VMEM ~1536;
//     MFMA 620 -> all overlap, step ~ 2200 cyc
//   - ysm all-lane epilogue + 2 lgkm-ONLY barriers (R3-proven); out-store and
//     xp prefetch float across barriers on counted vmcnt (compiler-inserted)

#define REP16(M) M(0) M(1) M(2) M(3) M(4) M(5) M(6) M(7) \
                 M(8) M(9) M(10) M(11) M(12) M(13) M(14) M(15)

#define LDW(jt, kt) (*reinterpret_cast<const bf16x8*>( \
    whhb + (size_t)(w * 64 + (jt) * 16 + r16) * H_SZ + (kt) * 32 + q * 8))

#define DECL3(k) bf16x8 rA##k, rB##k, rC##k;
#define LOAD3(k) { \
    bf16x8 t0 = LDW(0, k), t1 = LDW(1, k), t2 = LDW(2, k); \
    asm("" : "=a"(rA##k) : "0"(t0)); \
    asm("" : "=a"(rB##k) : "0"(t1)); \
    asm("" : "=a"(rC##k) : "0"(t2)); }

#define MFMA_B(A, B, C) __builtin_amdgcn_mfma_f32_16x16x32_bf16((A), (B), (C), 0, 0, 0)

// k = 0..3: jt3 from LDS
#define KSTEP_L(k) { \
    bf16x8 bf = *reinterpret_cast<const bf16x8*>(hb + (k) * 32 + q * 8); \
    bf16x8 al = *reinterpret_cast<const bf16x8*>(&WD[(w * 4 + (k)) * 512 + lane * 8]); \
    c0 = MFMA_B(rA##k, bf, c0); c1 = MFMA_B(rB##k, bf, c1); \
    c2 = MFMA_B(rC##k, bf, c2); c3 = MFMA_B(al,    bf, c3); }
// k = 4..15: jt3 from global (L2-resident, constant addresses)
#define KSTEP_G(k) { \
    bf16x8 bf = *reinterpret_cast<const bf16x8*>(hb + (k) * 32 + q * 8); \
    bf16x8 dl = LDW(3, k); \
    c0 = MFMA_B(rA##k, bf, c0); c1 = MFMA_B(rB##k, bf, c1); \
    c2 = MFMA_B(rC##k, bf, c2); c3 = MFMA_B(dl,    bf, c3); }

#define STEP(P, XP, sidx, CHKLAST)                                                          \
  {                                                                                          \
    const uint16_t* hb = &hsm[P][0];                                                         \
    f32x4 c0{0.f,0.f,0.f,0.f}, c1{0.f,0.f,0.f,0.f}, c2{0.f,0.f,0.f,0.f}, c3{0.f,0.f,0.f,0.f};\
    KSTEP_L(0)  KSTEP_L(1)  KSTEP_L(2)  KSTEP_L(3)                                           \
    KSTEP_G(4)  KSTEP_G(5)  KSTEP_G(6)  KSTEP_G(7)                                           \
    KSTEP_G(8)  KSTEP_G(9)  KSTEP_G(10) KSTEP_G(11)                                          \
    KSTEP_G(12) KSTEP_G(13) KSTEP_G(14) KSTEP_G(15)                                          \
    if (r16 == 0) {                                                                          \
      *reinterpret_cast<f32x4*>(&ysm[w * 64 +  0 + q * 4]) = c0;                             \
      *reinterpret_cast<f32x4*>(&ysm[w * 64 + 16 + q * 4]) = c1;                             \
      *reinterpret_cast<f32x4*>(&ysm[w * 64 + 32 + q * 4]) = c2;                             \
      *reinterpret_cast<f32x4*>(&ysm[w * 64 + 48 + q * 4]) = c3;                             \
    }                                                                                        \
    asm volatile("s_waitcnt lgkmcnt(0)" ::: "memory");                                       \
    __builtin_amdgcn_s_barrier();                                                            \
    float th = tfun(ysm[tid] + XP);                                                          \
    out[((size_t)(sidx) * B_SZ + b) * H_SZ + tid] = th;                                      \
    hsm[(P) ^ 1][tid] = f2b(th);                                                             \
    if (CHKLAST && (sidx) == S_LEN - 1)                                                      \
      out[(size_t)S_LEN * B_SZ * H_SZ + (size_t)b * H_SZ + tid] = th;                        \
    { int prow = ((sidx) + 2 < S_LEN) ? ((sidx) + 2) : 0;                                    \
      XP = out[((size_t)prow * B_SZ + b) * H_SZ + tid]; }                                    \
    asm volatile("s_waitcnt lgkmcnt(0)" ::: "memory");                                       \
    __builtin_amdgcn_s_barrier();                                                            \
  }

__global__ __launch_bounds__(512)
__attribute__((amdgpu_waves_per_eu(2, 2)))
void rnn_rec_kernel(const uint16_t* __restrict__ whhb,  // [H, H] bf16
                    const float* __restrict__ hx,       // [B, H] f32
                    float* __restrict__ out)            // [S*B*H | B*H] f32
{
    __shared__ __align__(16) uint16_t WD[8 * 4 * 512];   // 32 KB: per-wave jt3 kt0..3
    __shared__ __align__(16) uint16_t hsm[2][512];       // h bf16, double-buffered
    __shared__ __align__(16) float    ysm[512];          // y = Whh @ h

    const int tid  = threadIdx.x;   // 0..511
    const int lane = tid & 63;
    const int w    = tid >> 6;      // wave 0..7 -> rows [w*64, w*64+64)
    const int b    = blockIdx.x;    // batch
    const int r16  = lane & 15;
    const int q    = lane >> 4;     // 0..3

    // W jt0..2 pinned in AGPRs: rows j = w*64 + jt*16 + r16, k = kt*32 + q*8 + e
    REP16(DECL3)
    REP16(LOAD3)

    // W jt3, kt = 0..3 -> LDS (rest read from global each step)
#pragma unroll
    for (int kt = 0; kt < 4; ++kt)
        *reinterpret_cast<bf16x8*>(&WD[(w * 4 + kt) * 512 + lane * 8]) = LDW(3, kt);

    hsm[0][tid] = f2b(hx[(size_t)b * H_SZ + tid]);

    float xpA = out[((size_t)0 * B_SZ + b) * H_SZ + tid];
    float xpB = out[((size_t)1 * B_SZ + b) * H_SZ + tid];
    __syncthreads();

    for (int s = 0; s < S_LEN; s += 2) {
        STEP(0, xpA, s, 0)
        STEP(1, xpB, s + 1, 1)
    }
}

// ---------------- launcher ----------------
extern "C" void kernel_launch(void* const* d_in, const int* in_sizes, int n_in,
                              void* d_out, int out_size, void* d_ws, size_t ws_size,
                              hipStream_t stream) {
    const float* inp = (const float*)d_in[0];
    const float* hx  = (const float*)d_in[1];
    const float* wih = (const float*)d_in[2];
    const float* whh = (const float*)d_in[3];
    const float* bih = (const float*)d_in[4];
    const float* bhh = (const float*)d_in[5];
    float* out = (float*)d_out;

    uint16_t* whhb = (uint16_t*)d_ws;                    // 512 KB

    cvt_weights_kernel<<<256, 256, 0, stream>>>(whh, whhb);

    const int grid_gemm = (S_LEN * B_SZ / BM) * (H_SZ / BN);  // 4096
    xproj_gemm_kernel<<<grid_gemm, 256, 0, stream>>>(inp, wih, bih, bhh, out);

    rnn_rec_kernel<<<B_SZ, 512, 0, stream>>>(whhb, hx, out);
}

// Round 11
// 3284.675 us; speedup vs baseline: 1.7100x; 1.7100x over previous
//
#include <hip/hip_runtime.h>
#include <stdint.h>

#define S_LEN 2048
#define B_SZ  64
#define I_SZ  512
#define H_SZ  512

typedef __attribute__((ext_vector_type(8))) short bf16x8;
typedef __attribute__((ext_vector_type(4))) float f32x4;
typedef __attribute__((ext_vector_type(2))) unsigned int u32x2;

__device__ __forceinline__ uint16_t f2b(float x) {
    uint32_t u = __float_as_uint(x);
    uint32_t r = (u + 0x7fffu + ((u >> 16) & 1u)) >> 16;
    return (uint16_t)r;
}

__device__ __forceinline__ float tfun(float v) {
    float e = __expf(2.f * v);
    return 1.f - 2.f / (e + 1.f);
}

// ---------------- kernel 1: convert W_hh to bf16 in ws ----------------
__global__ void cvt_weights_kernel(const float* __restrict__ whh,
                                   uint16_t* __restrict__ whhb) {
    int i = (blockIdx.x * blockDim.x + threadIdx.x) * 4;
    float4 b = *reinterpret_cast<const float4*>(whh + i);
    union { uint16_t u[4]; uint2 v; } pb;
    pb.u[0] = f2b(b.x); pb.u[1] = f2b(b.y); pb.u[2] = f2b(b.z); pb.u[3] = f2b(b.w);
    *reinterpret_cast<uint2*>(whhb + i) = pb.v;
}

// ---------------- kernel 2: x_proj GEMM (f32 in, cvt on the fly) ----
#define BM 128
#define BN 128
#define BK 32

__launch_bounds__(256)
__global__ void xproj_gemm_kernel(const float* __restrict__ inp,      // [SB, I] f32
                                  const float* __restrict__ wih,      // [H, I] f32
                                  const float* __restrict__ bih,
                                  const float* __restrict__ bhh,
                                  float* __restrict__ xp)             // [SB, H] f32 (= d_out)
{
    __shared__ __align__(16) uint16_t Asm[2][BM * BK];
    __shared__ __align__(16) uint16_t Bsm[2][BN * BK];

    const int tid  = threadIdx.x;
    const int lane = tid & 63;
    const int w    = tid >> 6;
    const int wm   = (w >> 1) * 64;
    const int wn   = (w & 1) * 64;
    const int bid  = blockIdx.x;
    const int m0   = (bid >> 2) * BM;
    const int n0   = (bid & 3) * BN;

    const int srow  = tid >> 1;
    const int shalf = (tid & 1) * 16;

    float bsum[4];
#pragma unroll
    for (int nn = 0; nn < 4; ++nn) {
        int col = n0 + wn + nn * 16 + (lane & 15);
        bsum[nn] = bih[col] + bhh[col];
    }

    f32x4 acc[4][4];
#pragma unroll
    for (int mm = 0; mm < 4; ++mm)
#pragma unroll
        for (int nn = 0; nn < 4; ++nn)
            acc[mm][nn] = f32x4{0.f, 0.f, 0.f, 0.f};

    float4 ar[4], br[4];

    auto loadA = [&](int kt) {
        const float* g = inp + (size_t)(m0 + srow) * I_SZ + kt * BK + shalf;
#pragma unroll
        for (int q = 0; q < 4; ++q) ar[q] = *reinterpret_cast<const float4*>(g + q * 4);
    };
    auto loadB = [&](int kt) {
        const float* g = wih + (size_t)(n0 + srow) * I_SZ + kt * BK + shalf;
#pragma unroll
        for (int q = 0; q < 4; ++q) br[q] = *reinterpret_cast<const float4*>(g + q * 4);
    };
    auto cvt16 = [&](float4* src, uint16_t* dst) {
        alignas(16) uint16_t tmp[16];
#pragma unroll
        for (int q = 0; q < 4; ++q) {
            tmp[q * 4 + 0] = f2b(src[q].x); tmp[q * 4 + 1] = f2b(src[q].y);
            tmp[q * 4 + 2] = f2b(src[q].z); tmp[q * 4 + 3] = f2b(src[q].w);
        }
        *reinterpret_cast<bf16x8*>(dst)     = *reinterpret_cast<bf16x8*>(tmp);
        *reinterpret_cast<bf16x8*>(dst + 8) = *reinterpret_cast<bf16x8*>(tmp + 8);
    };
    auto writeA = [&](int buf) { cvt16(ar, &Asm[buf][srow * BK + shalf]); };
    auto writeB = [&](int buf) { cvt16(br, &Bsm[buf][srow * BK + shalf]); };

    loadA(0); loadB(0); writeA(0); writeB(0);
    __syncthreads();

    for (int kt = 0; kt < I_SZ / BK; ++kt) {
        const int cur = kt & 1;
        const bool more = (kt + 1) < I_SZ / BK;
        if (more) { loadA(kt + 1); loadB(kt + 1); }

        bf16x8 afrag[4], bfrag[4];
#pragma unroll
        for (int mm = 0; mm < 4; ++mm)
            afrag[mm] = *reinterpret_cast<const bf16x8*>(
                &Asm[cur][(wm + mm * 16 + (lane & 15)) * BK + (lane >> 4) * 8]);
#pragma unroll
        for (int nn = 0; nn < 4; ++nn)
            bfrag[nn] = *reinterpret_cast<const bf16x8*>(
                &Bsm[cur][(wn + nn * 16 + (lane & 15)) * BK + (lane >> 4) * 8]);
#pragma unroll
        for (int mm = 0; mm < 4; ++mm)
#pragma unroll
            for (int nn = 0; nn < 4; ++nn)
                acc[mm][nn] = __builtin_amdgcn_mfma_f32_16x16x32_bf16(
                    afrag[mm], bfrag[nn], acc[mm][nn], 0, 0, 0);

        if (more) { writeA(cur ^ 1); writeB(cur ^ 1); }
        __syncthreads();
    }

#pragma unroll
    for (int mm = 0; mm < 4; ++mm) {
        const int rbase = m0 + wm + mm * 16 + (lane >> 4) * 4;
#pragma unroll
        for (int nn = 0; nn < 4; ++nn) {
            const int col = n0 + wn + nn * 16 + (lane & 15);
#pragma unroll
            for (int r = 0; r < 4; ++r)
                xp[(size_t)(rbase + r) * H_SZ + col] = acc[mm][nn][r] + bsum[nn];
        }
    }
}

// ---------------- kernel 3: recurrence ----------------
// Clean floor experiment. Per wave per step:
//   - W jt0..2: 48 frags in AGPRs, STRONG pin (inline-asm MFMA "a" sources at
//     every use -> live range cannot leave AGPR; numerics proven R7/R9)
//   - W jt3: 16 frags from LDS (the only sustainable stream: LDS ~85 B/cyc/CU
//     beats L2 ~14 B/cyc/CU for CU-shared data — R10 evidence)
//   - h: LDS hsm double-buffer, 16 b128 broadcast reads (structural minimum)
//   - c3 accumulator uses BUILTIN mfma (compiler owns its hazards)
//   - act-lane fused epilogue (lanes r16<4 own c-frag r16: MFMA columns are
//     broadcast-identical): tanh + out float4 store + hsm bf16 write + xp
//     prefetch 2 steps ahead. ONE lgkm-only barrier per step; global traffic
//     floats across barriers on compiler-counted vmcnt.
// Register budget: 192 AGPR + ~64 arch = 256/wave at 2 waves/SIMD.

#define REP16(M) M(0) M(1) M(2) M(3) M(4) M(5) M(6) M(7) \
                 M(8) M(9) M(10) M(11) M(12) M(13) M(14) M(15)

#define LDW(jt, kt) (*reinterpret_cast<const bf16x8*>( \
    whhb + (size_t)(w * 64 + (jt) * 16 + r16) * H_SZ + (kt) * 32 + q * 8))

#define DECL3(k) bf16x8 rA##k, rB##k, rC##k;
#define LOAD3(k) { \
    bf16x8 t0 = LDW(0, k), t1 = LDW(1, k), t2 = LDW(2, k); \
    asm("" : "=a"(rA##k) : "0"(t0)); \
    asm("" : "=a"(rB##k) : "0"(t1)); \
    asm("" : "=a"(rC##k) : "0"(t2)); }

#define MFMA_B(A, B, C) __builtin_amdgcn_mfma_f32_16x16x32_bf16((A), (B), (C), 0, 0, 0)

#define MFMA3 \
    "v_mfma_f32_16x16x32_bf16 %0, %3, %6, %0\n\t" \
    "v_mfma_f32_16x16x32_bf16 %1, %4, %6, %1\n\t" \
    "v_mfma_f32_16x16x32_bf16 %2, %5, %6, %2"

// k=0: leading s_nop covers VALU zero-init -> asm-MFMA srcC hazard (R4 lesson)
#define KF(P, k) { \
    bf16x8 bf = *reinterpret_cast<const bf16x8*>(hb + (k) * 32 + q * 8); \
    bf16x8 al = *reinterpret_cast<const bf16x8*>(&WD[(w * 16 + (k)) * 512 + lane * 8]); \
    asm("s_nop 3\n\t" MFMA3 \
        : "+v"(c0), "+v"(c1), "+v"(c2) \
        : "a"(rA##k), "a"(rB##k), "a"(rC##k), "v"(bf)); \
    c3 = MFMA_B(al, bf, c3); }
#define KM(P, k) { \
    bf16x8 bf = *reinterpret_cast<const bf16x8*>(hb + (k) * 32 + q * 8); \
    bf16x8 al = *reinterpret_cast<const bf16x8*>(&WD[(w * 16 + (k)) * 512 + lane * 8]); \
    asm(MFMA3 \
        : "+v"(c0), "+v"(c1), "+v"(c2) \
        : "a"(rA##k), "a"(rB##k), "a"(rC##k), "v"(bf)); \
    c3 = MFMA_B(al, bf, c3); }
// k=15: trailing s_nops cover asm-MFMA D -> epilogue VALU read (R7-proven)
#define KL(P, k) { \
    bf16x8 bf = *reinterpret_cast<const bf16x8*>(hb + (k) * 32 + q * 8); \
    bf16x8 al = *reinterpret_cast<const bf16x8*>(&WD[(w * 16 + (k)) * 512 + lane * 8]); \
    asm(MFMA3 "\n\ts_nop 7\n\ts_nop 7" \
        : "+v"(c0), "+v"(c1), "+v"(c2) \
        : "a"(rA##k), "a"(rB##k), "a"(rC##k), "v"(bf)); \
    c3 = MFMA_B(al, bf, c3); }

#define STEP(P, XP, OP, sidx)                                                                \
  {                                                                                          \
    const uint16_t* hb = &hsm[P][0];                                                         \
    f32x4 c0{0.f,0.f,0.f,0.f}, c1{0.f,0.f,0.f,0.f}, c2{0.f,0.f,0.f,0.f}, c3{0.f,0.f,0.f,0.f};\
    KF(P, 0)                                                                                 \
    KM(P, 1)  KM(P, 2)  KM(P, 3)  KM(P, 4)  KM(P, 5)  KM(P, 6)  KM(P, 7)                     \
    KM(P, 8)  KM(P, 9)  KM(P, 10) KM(P, 11) KM(P, 12) KM(P, 13) KM(P, 14)                    \
    KL(P, 15)                                                                                \
    if (act) {                                                                               \
      f32x4 my = (r16 == 0) ? c0 : (r16 == 1) ? c1 : (r16 == 2) ? c2 : c3;                   \
      f32x4 o4;                                                                              \
      o4[0] = tfun(my[0] + XP[0]); o4[1] = tfun(my[1] + XP[1]);                              \
      o4[2] = tfun(my[2] + XP[2]); o4[3] = tfun(my[3] + XP[3]);                              \
      *reinterpret_cast<f32x4*>(OP) = o4;                                                    \
      u32x2 hp;                                                                              \
      hp[0] = (uint32_t)f2b(o4[0]) | ((uint32_t)f2b(o4[1]) << 16);                           \
      hp[1] = (uint32_t)f2b(o4[2]) | ((uint32_t)f2b(o4[3]) << 16);                           \
      *reinterpret_cast<u32x2*>(&hsm[(P) ^ 1][j0]) = hp;                                     \
      if ((sidx) + 2 < S_LEN)                                                                \
        XP = *reinterpret_cast<const f32x4*>(OP + 2 * B_SZ * H_SZ);                          \
      if ((sidx) == S_LEN - 1)                                                               \
        *reinterpret_cast<f32x4*>(out + (size_t)S_LEN * B_SZ * H_SZ +                        \
                                  (size_t)b * H_SZ + j0) = o4;                               \
    }                                                                                        \
    OP += 2 * B_SZ * H_SZ;                                                                   \
    asm volatile("s_waitcnt lgkmcnt(0)" ::: "memory");                                       \
    __builtin_amdgcn_s_barrier();                                                            \
  }

__global__ __launch_bounds__(512)
__attribute__((amdgpu_waves_per_eu(2, 2)))
void rnn_rec_kernel(const uint16_t* __restrict__ whhb,  // [H, H] bf16
                    const float* __restrict__ hx,       // [B, H] f32
                    float* __restrict__ out)            // [S*B*H | B*H] f32
{
    __shared__ __align__(16) uint16_t WD[8 * 16 * 512];  // 128 KB: per-wave W jt3
    __shared__ __align__(16) uint16_t hsm[2][512];       // h bf16, double-buffered

    const int tid  = threadIdx.x;   // 0..511
    const int lane = tid & 63;
    const int w    = tid >> 6;      // wave 0..7 -> rows [w*64, w*64+64)
    const int b    = blockIdx.x;    // batch
    const int r16  = lane & 15;
    const int q    = lane >> 4;     // 0..3

    // W jt0..2 pinned in AGPRs: rows j = w*64 + jt*16 + r16, k = kt*32 + q*8 + e
    REP16(DECL3)
    REP16(LOAD3)

    // W jt3 (rows w*64+48..63) -> LDS
#pragma unroll
    for (int kt = 0; kt < 16; ++kt)
        *reinterpret_cast<bf16x8*>(&WD[(w * 16 + kt) * 512 + lane * 8]) = LDW(3, kt);

    hsm[0][tid] = f2b(hx[(size_t)b * H_SZ + tid]);

    // epilogue ownership: lanes r16<4 own c-frag r16 -> rows j0..j0+3
    const bool act = (r16 < 4);
    const int  j0  = w * 64 + r16 * 16 + q * 4;

    float* opA = out + (size_t)b * H_SZ + j0;    // out row 0 (+= 2 rows per 2-step)
    float* opB = opA + (size_t)B_SZ * H_SZ;      // out row 1
    f32x4 XPA{0.f, 0.f, 0.f, 0.f}, XPB{0.f, 0.f, 0.f, 0.f};
    if (act) {
        XPA = *reinterpret_cast<const f32x4*>(opA);
        XPB = *reinterpret_cast<const f32x4*>(opB);
    }
    __syncthreads();

    for (int s = 0; s < S_LEN; s += 2) {
        STEP(0, XPA, opA, s)
        STEP(1, XPB, opB, s + 1)
    }
}

// ---------------- launcher ----------------
extern "C" void kernel_launch(void* const* d_in, const int* in_sizes, int n_in,
                              void* d_out, int out_size, void* d_ws, size_t ws_size,
                              hipStream_t stream) {
    const float* inp = (const float*)d_in[0];
    const float* hx  = (const float*)d_in[1];
    const float* wih = (const float*)d_in[2];
    const float* whh = (const float*)d_in[3];
    const float* bih = (const float*)d_in[4];
    const float* bhh = (const float*)d_in[5];
    float* out = (float*)d_out;

    uint16_t* whhb = (uint16_t*)d_ws;                    // 512 KB

    cvt_weights_kernel<<<256, 256, 0, stream>>>(whh, whhb);

    const int grid_gemm = (S_LEN * B_SZ / BM) * (H_SZ / BN);  // 4096
    xproj_gemm_kernel<<<grid_gemm, 256, 0, stream>>>(inp, wih, bih, bhh, out);

    rnn_rec_kernel<<<B_SZ, 512, 0, stream>>>(whhb, hx, out);
}